// Round 9
// baseline (442.018 us; speedup 1.0000x reference)
//
#include <hip/hip_runtime.h>
#include <hip/hip_bf16.h>
#include <math.h>

typedef __attribute__((ext_vector_type(2))) float    f32x2;
typedef __attribute__((ext_vector_type(4))) float    f32x4;
typedef __attribute__((ext_vector_type(16))) float   f32x16;
typedef __attribute__((ext_vector_type(4))) int      i32x4;
typedef __attribute__((ext_vector_type(8))) short    s16x8;
typedef __attribute__((ext_vector_type(4))) short    s16x4;
typedef __attribute__((ext_vector_type(8))) __bf16   bf16x8;

#define LOG2E 1.4426950408889634f

__device__ __forceinline__ short f32_to_bf16_rne(float f) {
    unsigned u = __builtin_bit_cast(unsigned, f);
    u += 0x7fffu + ((u >> 16) & 1u);
    return (short)(u >> 16);
}
__device__ __forceinline__ int pack2_bf16(float f0, float f1) {
    unsigned u0 = __builtin_bit_cast(unsigned, f0) + 0x8000u;   // round-half-up
    unsigned u1 = __builtin_bit_cast(unsigned, f1) + 0x8000u;
    return (int)((u0 >> 16) | (u1 & 0xffff0000u));
}
__device__ __forceinline__ bf16x8 as_bf16x8(s16x8 v) {
    return __builtin_bit_cast(bf16x8, v);
}
__device__ __forceinline__ bf16x8 as_bf16x8(i32x4 v) {
    return __builtin_bit_cast(bf16x8, v);
}

// ---------------- k0: W (f32 [k][col]) -> WT bf16 [col][k] ----------------
__global__ void k0_wt(const float* __restrict__ W, short* __restrict__ WT) {
    int g = blockIdx.x * 256 + threadIdx.x;     // 0..8191
    int col = g >> 6;
    int k0 = (g & 63) * 4;
    s16x4 v;
    #pragma unroll
    for (int i = 0; i < 4; ++i) v[i] = f32_to_bf16_rne(W[(k0 + i) * 128 + col]);
    *(s16x4*)(WT + col * 256 + k0) = v;
}

// ---------------- k1: Wh = h@W (MFMA), emit WhT bf16 [b][col][n], Wh1', Wh2' ----------------
__global__ __launch_bounds__(256, 2) void k1_gemm(
    const float* __restrict__ h, const float* __restrict__ a,
    const short* __restrict__ WT,
    short* __restrict__ WhT, float* __restrict__ Wh1p, float* __restrict__ Tp)
{
    int l = threadIdx.x & 63;
    int w = threadIdx.x >> 6;
    int gw = blockIdx.x * 4 + w;
    int r0 = gw * 16;                  // global row base (b*4096+n), multiple of 16
    int lm = l & 15, q = l >> 4;

    f32x4 acc[8];
    #pragma unroll
    for (int ct = 0; ct < 8; ++ct) acc[ct] = (f32x4)0.0f;

    const float* hrow = h + (long)(r0 + lm) * 256;
    for (int kb = 0; kb < 8; ++kb) {
        int kbase = kb * 32 + q * 8;
        f32x4 h0 = *(const f32x4*)(hrow + kbase);
        f32x4 h1 = *(const f32x4*)(hrow + kbase + 4);
        s16x8 af;
        #pragma unroll
        for (int j = 0; j < 4; ++j) af[j] = f32_to_bf16_rne(h0[j]);
        #pragma unroll
        for (int j = 0; j < 4; ++j) af[4 + j] = f32_to_bf16_rne(h1[j]);
        bf16x8 afb = as_bf16x8(af);
        #pragma unroll
        for (int ct = 0; ct < 8; ++ct) {
            s16x8 bf = *(const s16x8*)(WT + (ct * 16 + lm) * 256 + kbase);
            acc[ct] = __builtin_amdgcn_mfma_f32_16x16x32_bf16(afb, as_bf16x8(bf), acc[ct], 0, 0, 0);
        }
    }

    int b = r0 >> 12;
    int nb = r0 & 4095;
    float p1[4] = {0.f, 0.f, 0.f, 0.f}, p2[4] = {0.f, 0.f, 0.f, 0.f};
    #pragma unroll
    for (int ct = 0; ct < 8; ++ct) {
        int col = ct * 16 + lm;
        float a1c = a[col], a2c = a[128 + col];
        s16x4 vv;
        #pragma unroll
        for (int r = 0; r < 4; ++r) {
            float v = acc[ct][r];
            p1[r] += v * a1c;
            p2[r] += v * a2c;
            vv[r] = f32_to_bf16_rne(v);
        }
        *(s16x4*)(WhT + ((long)(b * 128 + col) * 4096 + nb + q * 4)) = vv;
    }
    #pragma unroll
    for (int off = 1; off < 16; off <<= 1) {
        #pragma unroll
        for (int r = 0; r < 4; ++r) {
            p1[r] += __shfl_xor(p1[r], off);
            p2[r] += __shfl_xor(p2[r], off);
        }
    }
    if (lm == 0) {
        #pragma unroll
        for (int r = 0; r < 4; ++r) {
            int row = r0 + q * 4 + r;
            Wh1p[row] = LOG2E * p1[r];
            Tp[row]   = LOG2E * p2[r];
        }
    }
}

// ---------------- k2: per-batch max of Tp ----------------
__global__ void k2_tmax(const float* __restrict__ Tp, float* __restrict__ Tmax) {
    __shared__ float red[256];
    int b = blockIdx.x, t = threadIdx.x;
    float mx = -1e30f;
    for (int i = 0; i < 16; ++i) mx = fmaxf(mx, Tp[b * 4096 + t + i * 256]);
    red[t] = mx;
    __syncthreads();
    for (int s = 128; s > 0; s >>= 1) {
        if (t < s) red[t] = fmaxf(red[t], red[t + s]);
        __syncthreads();
    }
    if (t == 0) Tmax[b] = red[0];
}

// ---------------- k3: 32x32x16-MFMA attention, direct nt adj stream ----------------
// wave = 32 rows, block = 4 waves = 128 rows x 1024-m slice (SPLIT=4).
// Cross-barrier prefetch: glds(t+1) + adj(t+1, nt) issued before compute(t);
// loads can't sink past __syncthreads -> in flight a full compute phase.
template <int SPLIT>
__global__ __launch_bounds__(256, 2) void k3_attn(
    const int* __restrict__ adj, const short* __restrict__ WhT,
    const float* __restrict__ Wh1p, const float* __restrict__ Tp,
    const float* __restrict__ Tmax,
    float* __restrict__ U, float* __restrict__ Z)
{
    const int MSLICE = 4096 / SPLIT;       // 1024
    const int MT = 64;                     // m per tile
    const int NT = MSLICE / MT;            // 16 tiles
    __shared__ __align__(16) short tile[2][128 * MT];   // 2 x 16 KB
    __shared__ __align__(16) float tps[MSLICE];          // 4 KB

    int l = threadIdx.x & 63, w = threadIdx.x >> 6;
    int i31 = l & 31, h = l >> 5;
    int bid = blockIdx.x;
    int mh = bid & (SPLIT - 1);
    int rg = (bid / SPLIT) & 31;
    int b  = bid / (SPLIT * 32);
    int n0 = rg * 128;
    int mbase = mh * MSLICE;

    int n_lane = n0 + w * 32 + i31;
    float sp = Wh1p[b * 4096 + n_lane];
    float xm = sp + Tmax[b];
    float Mrow = fmaxf(xm, 0.2f * xm);

    // this lane's adj row, offset to its h-half within each 16-m kstep
    const int* adjrow = adj + ((long)(b * 4096 + n_lane) << 12) + mbase + h * 8;
    const short* whtb = WhT + (long)b * 128 * 4096 + mbase;

    // stage Tp slice to LDS (once)
    {
        const float* tg = Tp + b * 4096 + mbase;
        int i0 = threadIdx.x * 4;
        *(f32x4*)(tps + i0) = *(const f32x4*)(tg + i0);
    }

    f32x16 acc[4];
    #pragma unroll
    for (int ct = 0; ct < 4; ++ct) acc[ct] = (f32x16)0.0f;
    float z = 0.0f;

    auto stage = [&](short* dst, int m0) {      // m0 relative to mbase, 64-aligned
        #pragma unroll
        for (int j = 0; j < 4; ++j) {
            int cb = w * 32 + j * 8;            // 8 cols per instruction
            int col = cb + (l >> 3);
            int gch = (l & 7) ^ (col & 7);      // XOR-swizzled 16B chunk
            const short* gp = whtb + (long)col * 4096 + m0 + gch * 8;
            __builtin_amdgcn_global_load_lds(
                (const __attribute__((address_space(1))) void*)gp,
                (__attribute__((address_space(3))) void*)(dst + cb * MT), 16, 0, 0);
        }
    };
    auto ldadj = [&](i32x4* aj, int m0) {       // 8 x i32x4 = this lane's 32 m's
        #pragma unroll
        for (int ks = 0; ks < 4; ++ks) {
            aj[2 * ks]     = __builtin_nontemporal_load((const i32x4*)(adjrow + m0 + ks * 16));
            aj[2 * ks + 1] = __builtin_nontemporal_load((const i32x4*)(adjrow + m0 + ks * 16 + 4));
        }
    };

    auto compute = [&](const short* buf, const i32x4* aj, int mrel) {
        #pragma unroll
        for (int ks = 0; ks < 4; ++ks) {        // 16 m per kstep
            int mt = ks * 16 + h * 8;           // this lane's 8 m within tile
            const float* tp8 = tps + mrel + mt;
            f32x4 ta = *(const f32x4*)(tp8);
            f32x4 tb = *(const f32x4*)(tp8 + 4);
            i32x4 a0 = aj[2 * ks], a1 = aj[2 * ks + 1];
            float wv[8];
            float zs = 0.0f;
            #pragma unroll
            for (int j = 0; j < 8; ++j) {
                float tt = (j < 4) ? ta[j] : tb[j - 4];
                int sel = (j < 4) ? a0[j] : a1[j - 4];
                float y = sp + tt;
                float e = fmaxf(y, 0.2f * y) - Mrow;
                float v = __builtin_amdgcn_exp2f(e);
                v = (sel != 0) ? v : 0.0f;
                zs += v; wv[j] = v;
            }
            z += zs;
            i32x4 pk;
            pk[0] = pack2_bf16(wv[0], wv[1]);
            pk[1] = pack2_bf16(wv[2], wv[3]);
            pk[2] = pack2_bf16(wv[4], wv[5]);
            pk[3] = pack2_bf16(wv[6], wv[7]);
            bf16x8 ab = as_bf16x8(pk);
            #pragma unroll
            for (int ct = 0; ct < 4; ++ct) {
                int col = ct * 32 + i31;
                int pos = (ks * 2 + h) ^ (col & 7);
                s16x8 bf = *(const s16x8*)(buf + col * MT + pos * 8);
                acc[ct] = __builtin_amdgcn_mfma_f32_32x32x16_bf16(ab, as_bf16x8(bf), acc[ct], 0, 0, 0);
            }
        }
    };

    i32x4 ajA[8], ajB[8];
    stage(tile[0], 0);
    ldadj(ajA, 0);
    __syncthreads();

    #pragma unroll 1
    for (int t = 0; t < NT; t += 2) {
        int r1 = (t + 1) & (NT - 1);
        stage(tile[1], r1 * MT);
        ldadj(ajB, r1 * MT);
        __builtin_amdgcn_sched_barrier(0);
        compute(tile[0], ajA, t * MT);
        __syncthreads();
        int r2 = (t + 2) & (NT - 1);
        stage(tile[0], r2 * MT);
        ldadj(ajA, r2 * MT);
        __builtin_amdgcn_sched_barrier(0);
        compute(tile[1], ajB, r1 * MT);
        __syncthreads();
    }

    // z: halves h=0/h=1 hold complementary m-partials of row i31
    z += __shfl_xor(z, 32);

    int slice = b * SPLIT + mh;
    if (l < 32) Z[slice * 4096 + n0 + w * 32 + l] = z;
    float* ub = U + ((long)slice * 4096 + n0 + w * 32) * 128;
    #pragma unroll
    for (int ct = 0; ct < 4; ++ct) {
        int col = ct * 32 + i31;
        #pragma unroll
        for (int r = 0; r < 16; ++r) {
            int rowoff = (r & 3) + 8 * (r >> 2) + 4 * h;   // verified 32x32 C/D mapping
            __builtin_nontemporal_store(acc[ct][r], ub + rowoff * 128 + col);
        }
    }
}

// ---------------- k4: combine split-m slices + ELU (nt U loads) ----------------
template <int SPLIT>
__global__ void k4_combine(const float* __restrict__ U, const float* __restrict__ Z,
                           float* __restrict__ out) {
    long g = (long)blockIdx.x * 256 + threadIdx.x;   // float4 index
    long off = g * 4;
    long nf = off >> 7;                               // b*4096+n
    int b = (int)(nf >> 12), n = (int)(nf & 4095), col = (int)(off & 127);
    const long slice = (long)4096 * 128;
    long base0 = ((long)(b * SPLIT) * 4096 + n) * 128 + col;
    f32x4 s = (f32x4)0.0f;
    float zz = 0.0f;
    #pragma unroll
    for (int i = 0; i < SPLIT; ++i) {
        f32x4 u = __builtin_nontemporal_load((const f32x4*)(U + base0 + i * slice));
        s += u;
        zz += Z[(b * SPLIT + i) * 4096 + n];
    }
    f32x4 v;
    #pragma unroll
    for (int i = 0; i < 4; ++i) {
        float x = s[i] / zz;
        v[i] = (x > 0.f) ? x : (expf(x) - 1.0f);
    }
    *(f32x4*)(out + off) = v;
}

extern "C" void kernel_launch(void* const* d_in, const int* in_sizes, int n_in,
                              void* d_out, int out_size, void* d_ws, size_t ws_size,
                              hipStream_t stream) {
    const float* h   = (const float*)d_in[0];
    const int*   adj = (const int*)d_in[1];
    const float* W   = (const float*)d_in[2];
    const float* a   = (const float*)d_in[3];
    float* out = (float*)d_out;

    char* ws = (char*)d_ws;
    short*    WhT  = (short*)ws;                          // 4 MB  bf16 [b][col][n]
    short*    WT   = (short*)(ws + 4194304);              // 64 KB bf16 [col][k]
    float*    Wh1p = (float*)(ws + 4259840);              // 64 KB log2e*Wh@a1
    float*    Tp   = (float*)(ws + 4325376);              // 64 KB log2e*Wh@a2
    float*    Tmax = (float*)(ws + 4390912);              // 16 B (+pad)
    float*    U    = (float*)(ws + 4391168);              // 32 MB (split=4)
    float*    Z    = (float*)(ws + 4391168 + 33554432);   // 256 KB

    k0_wt<<<32, 256, 0, stream>>>(W, WT);
    k1_gemm<<<256, 256, 0, stream>>>(h, a, WT, WhT, Wh1p, Tp);
    k2_tmax<<<4, 256, 0, stream>>>(Tp, Tmax);
    k3_attn<4><<<512, 256, 0, stream>>>(adj, WhT, Wh1p, Tp, Tmax, U, Z);
    k4_combine<4><<<2048, 256, 0, stream>>>(U, Z, out);
    (void)in_sizes; (void)n_in; (void)out_size; (void)ws_size;
}

// Round 10
// 405.269 us; speedup vs baseline: 1.0907x; 1.0907x over previous
//
#include <hip/hip_runtime.h>
#include <hip/hip_bf16.h>
#include <math.h>

typedef __attribute__((ext_vector_type(4))) float  f32x4;
typedef __attribute__((ext_vector_type(4))) int    i32x4;
typedef __attribute__((ext_vector_type(8))) short  s16x8;
typedef __attribute__((ext_vector_type(4))) short  s16x4;
typedef __attribute__((ext_vector_type(8))) __bf16 bf16x8;

#define LOG2E 1.4426950408889634f

__device__ __forceinline__ short f32_to_bf16_rne(float f) {
    unsigned u = __builtin_bit_cast(unsigned, f);
    u += 0x7fffu + ((u >> 16) & 1u);
    return (short)(u >> 16);
}
__device__ __forceinline__ int pack2_bf16(float f0, float f1) {
    unsigned u0 = __builtin_bit_cast(unsigned, f0) + 0x8000u;   // round-half-up
    unsigned u1 = __builtin_bit_cast(unsigned, f1) + 0x8000u;
    return (int)((u0 >> 16) | (u1 & 0xffff0000u));
}
__device__ __forceinline__ bf16x8 as_bf16x8(s16x8 v) {
    return __builtin_bit_cast(bf16x8, v);
}
__device__ __forceinline__ bf16x8 as_bf16x8(i32x4 v) {
    return __builtin_bit_cast(bf16x8, v);
}

// ---------------- k0: W (f32 [k][col]) -> WT bf16 [col][k] ----------------
__global__ void k0_wt(const float* __restrict__ W, short* __restrict__ WT) {
    int g = blockIdx.x * 256 + threadIdx.x;     // 0..8191
    int col = g >> 6;
    int k0 = (g & 63) * 4;
    s16x4 v;
    #pragma unroll
    for (int i = 0; i < 4; ++i) v[i] = f32_to_bf16_rne(W[(k0 + i) * 128 + col]);
    *(s16x4*)(WT + col * 256 + k0) = v;
}

// ---------------- k1: Wh = h@W (MFMA), emit WhT bf16 [b][col][n], Wh1', Wh2' ----------------
__global__ __launch_bounds__(256, 2) void k1_gemm(
    const float* __restrict__ h, const float* __restrict__ a,
    const short* __restrict__ WT,
    short* __restrict__ WhT, float* __restrict__ Wh1p, float* __restrict__ Tp)
{
    int l = threadIdx.x & 63;
    int w = threadIdx.x >> 6;
    int gw = blockIdx.x * 4 + w;
    int r0 = gw * 16;                  // global row base (b*4096+n), multiple of 16
    int lm = l & 15, q = l >> 4;

    f32x4 acc[8];
    #pragma unroll
    for (int ct = 0; ct < 8; ++ct) acc[ct] = (f32x4)0.0f;

    const float* hrow = h + (long)(r0 + lm) * 256;
    for (int kb = 0; kb < 8; ++kb) {
        int kbase = kb * 32 + q * 8;
        f32x4 h0 = *(const f32x4*)(hrow + kbase);
        f32x4 h1 = *(const f32x4*)(hrow + kbase + 4);
        s16x8 af;
        #pragma unroll
        for (int j = 0; j < 4; ++j) af[j] = f32_to_bf16_rne(h0[j]);
        #pragma unroll
        for (int j = 0; j < 4; ++j) af[4 + j] = f32_to_bf16_rne(h1[j]);
        bf16x8 afb = as_bf16x8(af);
        #pragma unroll
        for (int ct = 0; ct < 8; ++ct) {
            s16x8 bf = *(const s16x8*)(WT + (ct * 16 + lm) * 256 + kbase);
            acc[ct] = __builtin_amdgcn_mfma_f32_16x16x32_bf16(afb, as_bf16x8(bf), acc[ct], 0, 0, 0);
        }
    }

    int b = r0 >> 12;
    int nb = r0 & 4095;
    float p1[4] = {0.f, 0.f, 0.f, 0.f}, p2[4] = {0.f, 0.f, 0.f, 0.f};
    #pragma unroll
    for (int ct = 0; ct < 8; ++ct) {
        int col = ct * 16 + lm;
        float a1c = a[col], a2c = a[128 + col];
        s16x4 vv;
        #pragma unroll
        for (int r = 0; r < 4; ++r) {
            float v = acc[ct][r];
            p1[r] += v * a1c;
            p2[r] += v * a2c;
            vv[r] = f32_to_bf16_rne(v);
        }
        *(s16x4*)(WhT + ((long)(b * 128 + col) * 4096 + nb + q * 4)) = vv;
    }
    #pragma unroll
    for (int off = 1; off < 16; off <<= 1) {
        #pragma unroll
        for (int r = 0; r < 4; ++r) {
            p1[r] += __shfl_xor(p1[r], off);
            p2[r] += __shfl_xor(p2[r], off);
        }
    }
    if (lm == 0) {
        #pragma unroll
        for (int r = 0; r < 4; ++r) {
            int row = r0 + q * 4 + r;
            Wh1p[row] = LOG2E * p1[r];
            Tp[row]   = LOG2E * p2[r];
        }
    }
}

// ---------------- k2: per-batch max of Tp ----------------
__global__ void k2_tmax(const float* __restrict__ Tp, float* __restrict__ Tmax) {
    __shared__ float red[256];
    int b = blockIdx.x, t = threadIdx.x;
    float mx = -1e30f;
    for (int i = 0; i < 16; ++i) mx = fmaxf(mx, Tp[b * 4096 + t + i * 256]);
    red[t] = mx;
    __syncthreads();
    for (int s = 128; s > 0; s >>= 1) {
        if (t < s) red[t] = fmaxf(red[t], red[t + s]);
        __syncthreads();
    }
    if (t == 0) Tmax[b] = red[0];
}

// ---------------- k3: R5 structure (best measured) + nt U stores ----------------
// Per tile: issue glds(t+1 -> other buf) + adj(t+1 -> regs), compute(t), one barrier.
// Loads can't sink past __syncthreads -> in flight a full compute phase.
template <int SPLIT>
__global__ __launch_bounds__(256, 2) void k3_attn(
    const int* __restrict__ adj, const short* __restrict__ WhT,
    const float* __restrict__ Wh1p, const float* __restrict__ Tp,
    const float* __restrict__ Tmax,
    float* __restrict__ U, float* __restrict__ Z)
{
    const int MSLICE = 4096 / SPLIT;       // 2048
    const int MTILES = MSLICE / 128;       // 16
    __shared__ __align__(16) short tile[2][128 * 128];   // 64 KB B-tiles
    __shared__ __align__(16) float tps[4096 / SPLIT];    // 8 KB Tp slice

    int l = threadIdx.x & 63, w = threadIdx.x >> 6;
    int lm = l & 15, q = l >> 4;
    int bid = blockIdx.x;
    int mh = bid & (SPLIT - 1);
    int rg = (bid / SPLIT) & 63;
    int b  = bid / (SPLIT * 64);
    int n0 = rg * 64;
    int mbase = mh * MSLICE;

    int n_lane = n0 + w * 16 + lm;
    float sp = Wh1p[b * 4096 + n_lane];
    float xm = sp + Tmax[b];
    float Mrow = fmaxf(xm, 0.2f * xm);

    const int*   adjrow = adj + ((long)(b * 4096 + n_lane) << 12) + q * 8;
    const short* whtb   = WhT + (long)b * 128 * 4096;
    const float* tpsq   = tps + q * 8;

    // stage Tp slice to LDS (once)
    {
        const float* tg = Tp + b * 4096 + mbase;
        int i0 = threadIdx.x * 4;
        *(f32x4*)(tps + i0)        = *(const f32x4*)(tg + i0);
        *(f32x4*)(tps + i0 + 1024) = *(const f32x4*)(tg + i0 + 1024);
    }

    f32x4 acc[8];
    #pragma unroll
    for (int ct = 0; ct < 8; ++ct) acc[ct] = (f32x4)0.0f;
    float z = 0.0f;

    auto stage = [&](short* dst, int m0) {
        int colw = w * 32;
        #pragma unroll
        for (int j = 0; j < 8; ++j) {
            int cb = colw + j * 4;
            int col = cb + q;
            int gch = lm ^ (col & 7);
            const short* gp = whtb + (long)col * 4096 + m0 + gch * 8;
            __builtin_amdgcn_global_load_lds(
                (const __attribute__((address_space(1))) void*)gp,
                (__attribute__((address_space(3))) void*)(dst + cb * 128), 16, 0, 0);
        }
    };
    auto ldadj = [&](i32x4* aj, int m0) {
        #pragma unroll
        for (int ks = 0; ks < 4; ++ks) {
            aj[2 * ks]     = *(const i32x4*)(adjrow + m0 + ks * 32);
            aj[2 * ks + 1] = *(const i32x4*)(adjrow + m0 + ks * 32 + 4);
        }
    };
    auto compute = [&](const short* buf, const i32x4* aj, int mrel) {
        #pragma unroll
        for (int ks = 0; ks < 4; ++ks) {
            f32x4 t0 = *(const f32x4*)(tpsq + mrel + ks * 32);
            f32x4 t1 = *(const f32x4*)(tpsq + mrel + ks * 32 + 4);
            i32x4 pk;
            float zs = 0.0f;
            #pragma unroll
            for (int half = 0; half < 2; ++half) {
                i32x4 a4 = aj[2 * ks + half];
                f32x4 t4 = half ? t1 : t0;
                float wv[4];
                #pragma unroll
                for (int j = 0; j < 4; ++j) {
                    float y = sp + t4[j];
                    float e = fmaxf(y, 0.2f * y) - Mrow;
                    float v = __builtin_amdgcn_exp2f(e);
                    v = (a4[j] != 0) ? v : 0.0f;
                    zs += v; wv[j] = v;
                }
                pk[half * 2]     = pack2_bf16(wv[0], wv[1]);
                pk[half * 2 + 1] = pack2_bf16(wv[2], wv[3]);
            }
            z += zs;
            bf16x8 ab = as_bf16x8(pk);
            #pragma unroll
            for (int ct = 0; ct < 8; ++ct) {
                int col = ct * 16 + lm;
                int pos = (ks * 4 + q) ^ (col & 7);
                s16x8 bf = *(const s16x8*)(buf + col * 128 + pos * 8);
                acc[ct] = __builtin_amdgcn_mfma_f32_16x16x32_bf16(ab, as_bf16x8(bf), acc[ct], 0, 0, 0);
            }
        }
    };

    i32x4 ajA[8], ajB[8];
    stage(tile[0], mbase);
    ldadj(ajA, mbase);
    __syncthreads();

    #pragma unroll 1
    for (int t = 0; t < MTILES; t += 2) {
        int r1 = (t + 1) & (MTILES - 1);
        stage(tile[1], mbase + r1 * 128);
        ldadj(ajB, mbase + r1 * 128);
        __builtin_amdgcn_sched_barrier(0);
        compute(tile[0], ajA, t * 128);
        __syncthreads();
        int r2 = (t + 2) & (MTILES - 1);
        stage(tile[0], mbase + r2 * 128);
        ldadj(ajA, mbase + r2 * 128);
        __builtin_amdgcn_sched_barrier(0);
        compute(tile[1], ajB, r1 * 128);
        __syncthreads();
    }

    // z reduction over q (lanes lm, lm+16, lm+32, lm+48 hold partials of same row)
    z += __shfl_xor(z, 16);
    z += __shfl_xor(z, 32);

    int slice = b * SPLIT + mh;
    if (l < 16) Z[slice * 4096 + n0 + w * 16 + lm] = z;
    float* ub = U + ((long)slice * 4096 + n0 + w * 16) * 128;
    #pragma unroll
    for (int ct = 0; ct < 8; ++ct) {
        int col = ct * 16 + lm;
        #pragma unroll
        for (int r = 0; r < 4; ++r)
            __builtin_nontemporal_store(acc[ct][r], ub + (q * 4 + r) * 128 + col);
    }
}

// ---------------- k4: combine split-m halves + ELU (nt U loads) ----------------
__global__ void k4_combine(const float* __restrict__ U, const float* __restrict__ Z,
                           float* __restrict__ out) {
    long g = (long)blockIdx.x * 256 + threadIdx.x;   // float4 index
    long off = g * 4;
    long nf = off >> 7;                               // b*4096+n
    int b = (int)(nf >> 12), n = (int)(nf & 4095), col = (int)(off & 127);
    long base0 = ((long)(b * 2) * 4096 + n) * 128 + col;
    f32x4 u0 = __builtin_nontemporal_load((const f32x4*)(U + base0));
    f32x4 u1 = __builtin_nontemporal_load((const f32x4*)(U + base0 + (long)4096 * 128));
    float zz = Z[(b * 2) * 4096 + n] + Z[(b * 2 + 1) * 4096 + n];
    f32x4 v;
    #pragma unroll
    for (int i = 0; i < 4; ++i) {
        float x = (u0[i] + u1[i]) / zz;
        v[i] = (x > 0.f) ? x : (expf(x) - 1.0f);
    }
    *(f32x4*)(out + off) = v;
}

extern "C" void kernel_launch(void* const* d_in, const int* in_sizes, int n_in,
                              void* d_out, int out_size, void* d_ws, size_t ws_size,
                              hipStream_t stream) {
    const float* h   = (const float*)d_in[0];
    const int*   adj = (const int*)d_in[1];
    const float* W   = (const float*)d_in[2];
    const float* a   = (const float*)d_in[3];
    float* out = (float*)d_out;

    char* ws = (char*)d_ws;
    short* WhT  = (short*)ws;                          // 4 MB  bf16 [b][col][n]
    short* WT   = (short*)(ws + 4194304);              // 64 KB bf16 [col][k]
    float* Wh1p = (float*)(ws + 4259840);              // 64 KB log2e*Wh@a1
    float* Tp   = (float*)(ws + 4325376);              // 64 KB log2e*Wh@a2
    float* Tmax = (float*)(ws + 4390912);              // 16 B (+pad)
    float* U    = (float*)(ws + 4391168);              // 16 MB (split=2)
    float* Z    = (float*)(ws + 4391168 + 16777216);   // 128 KB

    k0_wt<<<32, 256, 0, stream>>>(W, WT);
    k1_gemm<<<256, 256, 0, stream>>>(h, a, WT, WhT, Wh1p, Tp);
    k2_tmax<<<4, 256, 0, stream>>>(Tp, Tmax);
    k3_attn<2><<<512, 256, 0, stream>>>(adj, WhT, Wh1p, Tp, Tmax, U, Z);
    k4_combine<<<2048, 256, 0, stream>>>(U, Z, out);
    (void)in_sizes; (void)n_in; (void)out_size; (void)ws_size;
}